// Round 8
// baseline (2010.522 us; speedup 1.0000x reference)
//
#include <hip/hip_runtime.h>
#include <hip/hip_bf16.h>

typedef unsigned short u16;
typedef unsigned int u32;
typedef __attribute__((ext_vector_type(8))) short short8;
typedef __attribute__((ext_vector_type(4))) float f32x4;

#define NB 32
#define NC_ 512
#define HW 1024
#define NE 256
#define NA 32
#define NR 24
#define PW_ 256
#define MLAN 128
#define NV 56      // Lanczos vectors cached in LDS (f32)
#define NCACHE 12  // G rows per thread-slab cached in VGPRs (of 32)

__device__ inline float b2f(u16 u) { return __uint_as_float(((u32)u) << 16); }
__device__ inline u16 f2b(float f) {
    u32 x = __float_as_uint(f);
    u32 r = x + 0x7FFFu + ((x >> 16) & 1u);
    return (u16)(r >> 16);
}
__device__ inline float gelu_exact(float x) {
    return 0.5f * x * (1.0f + erff(x * 0.70710678118654752f));
}
__device__ inline float sigmoidf_(float x) { return 1.0f / (1.0f + expf(-x)); }

template <int NW>
__device__ inline float block_reduce_sum(float x, volatile float* red) {
#pragma unroll
    for (int m = 32; m >= 1; m >>= 1) x += __shfl_xor(x, m);
    const int lane = threadIdx.x & 63, wid = threadIdx.x >> 6;
    __syncthreads();
    if (lane == 0) red[wid] = x;
    __syncthreads();
    float s = 0.f;
#pragma unroll
    for (int i = 0; i < NW; i++) s += red[i];
    return s;
}

// ---------------- Gram: G[b] = X_b X_b^T / 1024, row-major bf16 ----------------
__global__ __launch_bounds__(256) void gram_kernel(const float* __restrict__ x,
                                                   u16* __restrict__ Gp) {
    __shared__ __align__(16) u16 Ai[128][72];
    __shared__ __align__(16) u16 Bj[128][72];
    const int b = blockIdx.y;
    const int i0 = (blockIdx.x >> 2) * 128;
    const int j0 = (blockIdx.x & 3) * 128;
    const int t = threadIdx.x;
    const int lane = t & 63, wid = t >> 6;
    const int wm = (wid >> 1) * 64, wn = (wid & 1) * 64;
    f32x4 acc[4][4] = {};
    const float* xb = x + (size_t)b * NC_ * HW;

    for (int kc = 0; kc < HW; kc += 64) {
#pragma unroll
        for (int i = 0; i < 8; i++) {
            int idx = t + 256 * i;  // 128 rows x 16 float4
            int r = idx >> 4, c4 = (idx & 15) * 4;
            float4 qa = *(const float4*)(xb + (size_t)(i0 + r) * HW + kc + c4);
            float4 qb = *(const float4*)(xb + (size_t)(j0 + r) * HW + kc + c4);
            Ai[r][c4 + 0] = f2b(qa.x); Ai[r][c4 + 1] = f2b(qa.y);
            Ai[r][c4 + 2] = f2b(qa.z); Ai[r][c4 + 3] = f2b(qa.w);
            Bj[r][c4 + 0] = f2b(qb.x); Bj[r][c4 + 1] = f2b(qb.y);
            Bj[r][c4 + 2] = f2b(qb.z); Bj[r][c4 + 3] = f2b(qb.w);
        }
        __syncthreads();
#pragma unroll
        for (int ks = 0; ks < 64; ks += 32) {
            const int kk = ks + (lane >> 4) * 8;
            short8 af[4], bf[4];
#pragma unroll
            for (int m = 0; m < 4; m++) af[m] = *(const short8*)&Ai[wm + m * 16 + (lane & 15)][kk];
#pragma unroll
            for (int n = 0; n < 4; n++) bf[n] = *(const short8*)&Bj[wn + n * 16 + (lane & 15)][kk];
#pragma unroll
            for (int m = 0; m < 4; m++)
#pragma unroll
                for (int n = 0; n < 4; n++)
                    acc[m][n] = __builtin_amdgcn_mfma_f32_16x16x32_bf16(af[m], bf[n], acc[m][n], 0, 0, 0);
        }
        __syncthreads();
    }
    const float scale = 1.0f / 1024.0f;
    u16* Gb = Gp + (size_t)b * NC_ * NC_;
#pragma unroll
    for (int m = 0; m < 4; m++) {
#pragma unroll
        for (int n = 0; n < 4; n++) {
            int row = i0 + wm + m * 16 + (lane >> 4) * 4;
            int col = j0 + wn + n * 16 + (lane & 15);
#pragma unroll
            for (int r = 0; r < 4; r++)
                Gb[(size_t)(row + r) * NC_ + col] = f2b(acc[m][n][r] * scale);
        }
    }
}

// ---------------- channel sums ----------------
__global__ __launch_bounds__(256) void colsum_kernel(const float* __restrict__ x,
                                                     float* __restrict__ cs) {
    const int row = blockIdx.x * 4 + (threadIdx.x >> 6);
    const int lane = threadIdx.x & 63;
    const float* p = x + (size_t)row * HW;
    float s = 0.f;
    for (int i = lane; i < HW; i += 64) s += p[i];
#pragma unroll
    for (int m = 32; m >= 1; m >>= 1) s += __shfl_xor(s, m);
    if (lane == 0) cs[row] = s;
}

// ---------------- Lanczos (m=128) + Sturm bisection ----------------
// R7 (resubmit after infra failure; race/OOB/termination audit clean):
//  (1) NCACHE=12 G-rows/thread cached in VGPRs (48 regs, bf16-pairs, fully
//      static unroll -- rule-#20-safe). Matvec L2 stream 512KB -> 320KB/iter.
//  (2) Fused dot+scatter reorth: each wave dots AND subtracts its i-subset
//      (i = wid mod 16), accumulating per-wave partial correction vectors in
//      scr[16][544] (reused matvec wpart buffer). V data read once, not twice.
//  (3) Unnormalized basis + scale tracking: store r-vectors with sc2[i]=1/b^2;
//      normalize on the fly (v = r*inv in regs). Kills the v-publish barrier.
//  Skip path = 4 barriers/iter (S1 wpart+alpha, S2 w+nb0, SA partials,
//  SB norm+w'). Separate red/red2/red3 rails avoid cross-phase races.
__global__ __launch_bounds__(1024, 4) void lanczos_kernel(const u16* __restrict__ Gp,
                                                          float* __restrict__ V,
                                                          float* __restrict__ svd_raw) {
    __shared__ __align__(16) float Vl[NV][512];   // 114688 B (unnormalized r's)
    __shared__ __align__(16) float w[512];        // 2048 B (current r)
    __shared__ float v2[528];                     // 2112 B (r transposed, stride 66)
    __shared__ __align__(16) float scr[16][544];  // 34816 B (wpart / reorth partials)
    __shared__ float red[16], red2[8], red3[8];
    __shared__ float al[MLAN], be[MLAN + 1], sc2_[MLAN + 1];
    const int b = blockIdx.x;
    const int t = threadIdx.x;
    const int lane = t & 63, wid = t >> 6;
    const int el = t & 511, half = t >> 9;
    const int e8 = el & 7, l8 = el >> 3;
    const u16* Gb = Gp + (size_t)b * NC_ * NC_;
    const u16* gp = Gb + (size_t)(wid * 32) * NC_ + lane * 8;  // this thread's slab
    float* Vb = V + (size_t)b * MLAN * 512;

    // cache rows 0..NCACHE-1 of the slab in VGPRs (static indices only)
    u32 gc[NCACHE * 4];
#pragma unroll
    for (int kk = 0; kk < NCACHE; kk++) {
        short8 g = *(const short8*)(gp + (size_t)kk * NC_);
        const u32* gu = (const u32*)&g;
        gc[kk * 4 + 0] = gu[0]; gc[kk * 4 + 1] = gu[1];
        gc[kk * 4 + 2] = gu[2]; gc[kk * 4 + 3] = gu[3];
    }

    u32 h = (u32)el * 2654435761u ^ ((u32)b * 0x9E3779B9u);
    h ^= h >> 16; h *= 0x85EBCA6Bu; h ^= h >> 13; h *= 0xC2B2AE35u; h ^= h >> 16;
    float vt0 = (float)(h & 0xFFFFFFu) * (1.0f / 16777216.0f) - 0.5f;
    float nrm = block_reduce_sum<16>(half == 0 ? vt0 * vt0 : 0.f, red);
    vt0 *= rsqrtf(nrm);
    if (half == 0) {
        w[el] = vt0;
        v2[e8 * 66 + l8] = vt0;
        Vl[0][el] = vt0;
    }
    if (t == 0) sc2_[0] = 1.0f;
    // per-thread scaled-basis state: rw/invc = current r element & 1/beta;
    // rwp/invp = previous. v_j[el] = rw*invc, v_{j-1}[el] = rwp*invp.
    float rw = vt0, invc = 1.0f, rwp = 0.f, invp = 0.f, beta = 0.f;
    __syncthreads();

    for (int j = 0; j < MLAN; j++) {
        // ---- matvec u' = G * r_{j-1}: streamed rows first (loads in flight),
        //      then VGPR-cached rows ----
        float a0 = 0.f, a1 = 0.f, a2 = 0.f, a3 = 0.f;
        float a4 = 0.f, a5 = 0.f, a6 = 0.f, a7 = 0.f;
        const float* vk = w + wid * 32;
#pragma unroll 5
        for (int kk = NCACHE; kk < 32; kk++) {
            short8 g = *(const short8*)(gp + (size_t)kk * NC_);
            float vv = vk[kk];
            a0 += b2f((u16)g[0]) * vv;
            a1 += b2f((u16)g[1]) * vv;
            a2 += b2f((u16)g[2]) * vv;
            a3 += b2f((u16)g[3]) * vv;
            a4 += b2f((u16)g[4]) * vv;
            a5 += b2f((u16)g[5]) * vv;
            a6 += b2f((u16)g[6]) * vv;
            a7 += b2f((u16)g[7]) * vv;
        }
#pragma unroll
        for (int kk = 0; kk < NCACHE; kk++) {
            float vv = vk[kk];
            u32 u0 = gc[kk * 4 + 0], u1 = gc[kk * 4 + 1];
            u32 u2 = gc[kk * 4 + 2], u3 = gc[kk * 4 + 3];
            a0 += __uint_as_float(u0 << 16) * vv;
            a1 += __uint_as_float(u0 & 0xFFFF0000u) * vv;
            a2 += __uint_as_float(u1 << 16) * vv;
            a3 += __uint_as_float(u1 & 0xFFFF0000u) * vv;
            a4 += __uint_as_float(u2 << 16) * vv;
            a5 += __uint_as_float(u2 & 0xFFFF0000u) * vv;
            a6 += __uint_as_float(u3 << 16) * vv;
            a7 += __uint_as_float(u3 & 0xFFFF0000u) * vv;
        }
        // wpart: column c = lane*8+e -> scr[wid][e*68+lane]
        scr[wid][0 * 68 + lane] = a0; scr[wid][1 * 68 + lane] = a1;
        scr[wid][2 * 68 + lane] = a2; scr[wid][3 * 68 + lane] = a3;
        scr[wid][4 * 68 + lane] = a4; scr[wid][5 * 68 + lane] = a5;
        scr[wid][6 * 68 + lane] = a6; scr[wid][7 * 68 + lane] = a7;
        // alpha partial: u' . r  via transposed copy v2 (conflict-free b32)
        float ap = a0 * v2[lane] + a1 * v2[66 + lane]
                 + a2 * v2[132 + lane] + a3 * v2[198 + lane]
                 + a4 * v2[264 + lane] + a5 * v2[330 + lane]
                 + a6 * v2[396 + lane] + a7 * v2[462 + lane];
#pragma unroll
        for (int m = 32; m >= 1; m >>= 1) ap += __shfl_xor(ap, m);
        if (lane == 0) red[wid] = ap;
        __syncthreads();  // S1: wpart + alpha partials

        float accp = 0.f;
#pragma unroll
        for (int p = 0; p < 16; p++) accp += scr[p][e8 * 68 + l8];  // u'_el
        float rawa = 0.f;
#pragma unroll
        for (int i = 0; i < 16; i++) rawa += red[i];  // u' . r
        const float alpha = rawa * invc * invc;
        float wt = accp * invc - alpha * (rw * invc) - beta * (rwp * invp);
        if (half == 0) w[el] = wt;
        float pz = wt * wt;
#pragma unroll
        for (int m = 32; m >= 1; m >>= 1) pz += __shfl_xor(pz, m);
        if (lane == 0 && wid < 8) red2[wid] = pz;
        __syncthreads();  // S2: w + nb0 partials
        float nb0 = 0.f;
#pragma unroll
        for (int i = 0; i < 8; i++) nb0 += red2[i];
        const float gscale = nb0 + alpha * alpha + beta * beta;

        float nb = 0.f;
        for (int pass = 0;; pass++) {
            // ---- fused dots + scatter: wave handles i in {wid, wid+16, ...} ----
            const float4 wv0 = *(const float4*)&w[lane * 4];
            const float4 wv1 = *(const float4*)&w[256 + lane * 4];
            float s0 = 0.f, s1 = 0.f, s2 = 0.f, s3 = 0.f;
            float s4 = 0.f, s5 = 0.f, s6 = 0.f, s7 = 0.f;
            for (int i = wid; i <= j; i += 16) {
                float4 x0, x1;
                if (i < NV) {
                    x0 = *(const float4*)&Vl[i][lane * 4];
                    x1 = *(const float4*)&Vl[i][256 + lane * 4];
                } else {
                    const float* Vi = Vb + (size_t)i * 512;
                    x0 = *(const float4*)(Vi + lane * 4);
                    x1 = *(const float4*)(Vi + 256 + lane * 4);
                }
                float p = x0.x * wv0.x + x0.y * wv0.y + x0.z * wv0.z + x0.w * wv0.w
                        + x1.x * wv1.x + x1.y * wv1.y + x1.z * wv1.z + x1.w * wv1.w;
#pragma unroll
                for (int m = 32; m >= 1; m >>= 1) p += __shfl_xor(p, m);
                const float ps = p * sc2_[i];  // <v_i,w> scale (unnormalized basis)
                s0 += ps * x0.x; s1 += ps * x0.y; s2 += ps * x0.z; s3 += ps * x0.w;
                s4 += ps * x1.x; s5 += ps * x1.y; s6 += ps * x1.z; s7 += ps * x1.w;
            }
            *(f32x4*)&scr[wid][lane * 4] = (f32x4){s0, s1, s2, s3};
            *(f32x4*)&scr[wid][256 + lane * 4] = (f32x4){s4, s5, s6, s7};
            __syncthreads();  // SA: partial corrections
            float sub = 0.f;
#pragma unroll
            for (int p16 = 0; p16 < 16; p16++) sub += scr[p16][el];
            wt = wt - sub;
            if (half == 0) {
                w[el] = wt;  // for (rare) pass 2 / next matvec
                v2[e8 * 66 + l8] = wt;
                if (j + 1 < NV) Vl[j + 1][el] = wt;
                else if (j + 1 < MLAN) Vb[(size_t)(j + 1) * 512 + el] = wt;
            }
            float pn = wt * wt;
#pragma unroll
            for (int m = 32; m >= 1; m >>= 1) pn += __shfl_xor(pn, m);
            if (lane == 0 && wid < 8) red3[wid] = pn;
            __syncthreads();  // SB: norm partials + w/v2/Vl
            nb = 0.f;
#pragma unroll
            for (int q = 0; q < 8; q++) nb += red3[q];
            // DGKS "twice is enough" with absolute cancellation guard
            if (pass == 1 || (nb > 0.5f * nb0 && nb0 > 1e-8f * gscale)) break;
            nb0 = nb;
        }
        float betn = sqrtf(nb);
        bool ok = (betn > 1e-20f) && (betn == betn) && !isinf(betn);
        if (t == 0) {
            al[j] = alpha;
            be[j + 1] = ok ? betn : 0.f;
            sc2_[j + 1] = ok ? 1.0f / nb : 0.f;
        }
        beta = ok ? betn : 0.f;
        rwp = rw; invp = invc;
        rw = wt;
        invc = ok ? 1.0f / betn : 0.f;
        // no barrier: next matvec reads w/v2 published before SB; sc2_[j+1]
        // and red rails are separated from their readers by >=1 barrier.
    }

    if (t < NR) {
        float lo = 1e30f, hi = -1e30f;
        for (int i = 0; i < MLAN; i++) {
            float bl = (i > 0) ? fabsf(be[i]) : 0.f;
            float br = (i + 1 < MLAN) ? fabsf(be[i + 1]) : 0.f;
            lo = fminf(lo, al[i] - bl - br);
            hi = fmaxf(hi, al[i] + bl + br);
        }
        const int i0 = MLAN - 1 - t;
        for (int it = 0; it < 30; it++) {
            float mid = 0.5f * (lo + hi);
            int cnt = 0;
            float d = 1.0f;
            for (int i = 0; i < MLAN; i++) {
                float bb2 = (i > 0) ? be[i] * be[i] : 0.f;
                float dp = d;
                if (fabsf(dp) < 1e-30f) dp = (dp < 0.f) ? -1e-30f : 1e-30f;
                d = (al[i] - mid) - bb2 / dp;
                cnt += (d < 0.f);
            }
            if (cnt > i0) hi = mid; else lo = mid;
        }
        float ev = fmaxf(0.5f * (lo + hi), 0.f);
        float val = log1pf(sqrtf(ev));
        if (!(val == val) || isinf(val)) val = 1.0f;
        svd_raw[b * NR + t] = val;
    }
}

// ---------------- emb -> cos -> top3 -> gate ----------------
__global__ __launch_bounds__(256) void embgate_kernel(
    const float* __restrict__ cs, const float* __restrict__ W_emb,
    const float* __restrict__ g_emb, const float* __restrict__ beta_emb,
    const float* __restrict__ anchors, float* __restrict__ tg_out) {
    const int b = blockIdx.x, t = threadIdx.x;
    __shared__ float csl[512], embv[256], cosv[32], tgs[32];
    __shared__ float red[4];

    for (int i = t; i < 512; i += 256) csl[i] = cs[b * 512 + i];
    __syncthreads();

    float e = 0.f;
    for (int c = 0; c < 512; c++) e += csl[c] * W_emb[c * NE + t];
    e *= (1.0f / 1024.0f);
    float mean = block_reduce_sum<4>(e, red) * (1.0f / 256.0f);
    float dv = e - mean;
    float var = block_reduce_sum<4>(dv * dv, red) * (1.0f / 256.0f);
    e = dv * rsqrtf(var + 1e-5f) * g_emb[t] + beta_emb[t];
    float nn = block_reduce_sum<4>(e * e, red);
    e = e / fmaxf(sqrtf(nn), 1e-12f);
    embv[t] = e;
    __syncthreads();

    if (t < 32) {
        float p = 0.f, na = 0.f;
        for (int q = 0; q < 256; q++) {
            float av = anchors[t * NE + q];
            p += embv[q] * av;
            na += av * av;
        }
        cosv[t] = p / fmaxf(sqrtf(na), 1e-12f);
    }
    __syncthreads();

    if (t == 0) {
        int i1 = 0, i2 = 0, i3 = 0;
        float v1 = -1e30f, v2 = -1e30f, v3 = -1e30f;
        for (int a = 0; a < 32; a++) {
            float cv = cosv[a];
            if (cv > v1) { v3 = v2; i3 = i2; v2 = v1; i2 = i1; v1 = cv; i1 = a; }
            else if (cv > v2) { v3 = v2; i3 = i2; v2 = cv; i2 = a; }
            else if (cv > v3) { v3 = cv; i3 = a; }
        }
        float e2 = expf(v2 - v1), e3 = expf(v3 - v1);
        float ss = 1.0f + e2 + e3;
        for (int a = 0; a < 32; a++) tgs[a] = 0.f;
        tgs[i1] = (1.0f - v1) * 1.0f / ss;
        tgs[i2] = (1.0f - v2) * e2 / ss;
        tgs[i3] = (1.0f - v3) * e3 / ss;
    }
    __syncthreads();
    if (t < 32) tg_out[b * 32 + t] = tgs[t];
}

// ---------------- compartment MLPs -> pw ----------------
__global__ __launch_bounds__(256) void mlp_kernel(
    const float* __restrict__ tg, const float* __restrict__ Wc1,
    const float* __restrict__ bc1, const float* __restrict__ Wc2,
    const float* __restrict__ bc2, const float* __restrict__ g_c,
    const float* __restrict__ beta_c, float* __restrict__ pw_out) {
    const int b = blockIdx.x, t = threadIdx.x;
    __shared__ float tgl[32], hbuf[512], pcb[256];

    if (t < 32) tgl[t] = tg[b * 32 + t];
    __syncthreads();

    for (int o = t; o < 512; o += 256) {
        int c = o >> 6, d = o & 63;
        float s = bc1[c * 64 + d];
        for (int a = 0; a < 32; a++) s += tgl[a] * Wc1[(c * 32 + a) * 64 + d];
        hbuf[o] = gelu_exact(s);
    }
    __syncthreads();

    const int c = t >> 5, e = t & 31;
    float s = bc2[c * 32 + e];
    for (int d = 0; d < 64; d++) s += hbuf[c * 64 + d] * Wc2[(c * 64 + d) * 32 + e];
    pcb[t] = s;
    __syncthreads();

    float mean = 0.f;
    for (int k = 0; k < 32; k++) mean += pcb[c * 32 + k];
    mean *= (1.0f / 32.0f);
    float var = 0.f;
    for (int k = 0; k < 32; k++) { float dd = pcb[c * 32 + k] - mean; var += dd * dd; }
    var *= (1.0f / 32.0f);
    pw_out[b * PW_ + t] = (s - mean) * rsqrtf(var + 1e-5f) * g_c[c * 32 + e] + beta_c[c * 32 + e];
}

// ---------------- svd_ctx ----------------
__global__ __launch_bounds__(256) void ctx_kernel(
    const float* __restrict__ svd_raw, const float* __restrict__ W_svd,
    const float* __restrict__ b_svd, const float* __restrict__ g_svd,
    const float* __restrict__ beta_svd, float* __restrict__ ctx_out) {
    const int b = blockIdx.x, t = threadIdx.x;
    __shared__ float rawv[NR];
    __shared__ float red[4];
    if (t < NR) rawv[t] = svd_raw[b * NR + t];
    __syncthreads();
    float sv = b_svd[t];
    for (int r = 0; r < NR; r++) sv += rawv[r] * W_svd[r * PW_ + t];
    float mean = block_reduce_sum<4>(sv, red) * (1.0f / 256.0f);
    float dv = sv - mean;
    float var = block_reduce_sum<4>(dv * dv, red) * (1.0f / 256.0f);
    ctx_out[b * PW_ + t] = gelu_exact(dv * rsqrtf(var + 1e-5f) * g_svd[t] + beta_svd[t]);
}

// ---------------- cw + geo_out (f32) ----------------
__global__ __launch_bounds__(256) void cwgeo_kernel(
    const float* __restrict__ pw, const float* __restrict__ ctx,
    const float* __restrict__ geo_state, const float* __restrict__ W_mod,
    const float* __restrict__ b_mod, const float* __restrict__ geo_gate,
    const float* __restrict__ W_geo, const float* __restrict__ b_geo,
    const float* __restrict__ g_geo, const float* __restrict__ beta_geo,
    float* __restrict__ cw, float* __restrict__ out_geo) {
    const int b = blockIdx.x, t = threadIdx.x;
    __shared__ float mi[768];
    __shared__ float red[4];
    mi[t] = pw[b * PW_ + t];
    mi[256 + t] = ctx[b * PW_ + t];
    float geo = geo_state[b * PW_ + t];
    mi[512 + t] = geo;
    __syncthreads();

    float gg = b_geo[t];
    for (int q = 0; q < PW_; q++) gg += mi[q] * W_geo[q * PW_ + t];
    float gmean = block_reduce_sum<4>(gg, red) * (1.0f / 256.0f);
    float gdv = gg - gmean;
    float gvar = block_reduce_sum<4>(gdv * gdv, red) * (1.0f / 256.0f);
    float lnv = gdv * rsqrtf(gvar + 1e-5f) * g_geo[t] + beta_geo[t];
    out_geo[b * PW_ + t] = geo + sigmoidf_(geo_gate[t]) * lnv;

    for (int c = t; c < 512; c += 256) {
        float s = b_mod[c];
        for (int k = 0; k < 768; k++) s += mi[k] * W_mod[k * NC_ + c];
        cw[b * NC_ + c] = sigmoidf_(s);
    }
}

// ---------------- x_out(f32) = x(f32) * cw[b,c] ----------------
__global__ __launch_bounds__(256) void modulate_kernel(const float* __restrict__ x,
                                                       const float* __restrict__ cw,
                                                       float* __restrict__ out) {
    const int i4 = blockIdx.x * 256 + threadIdx.x;  // float4 index
    const float4* xp = (const float4*)x;
    float4 q = xp[i4];
    const float wv = cw[i4 >> 8];  // (i4*4)>>10 = b*512+c
    float4 o;
    o.x = q.x * wv; o.y = q.y * wv; o.z = q.z * wv; o.w = q.w * wv;
    ((float4*)out)[i4] = o;
}

extern "C" void kernel_launch(void* const* d_in, const int* in_sizes, int n_in,
                              void* d_out, int out_size, void* d_ws, size_t ws_size,
                              hipStream_t stream) {
    const float* x = (const float*)d_in[0];
    const float* geo_state = (const float*)d_in[1];
    const float* W_svd = (const float*)d_in[2];
    const float* b_svd = (const float*)d_in[3];
    const float* g_svd = (const float*)d_in[4];
    const float* beta_svd = (const float*)d_in[5];
    const float* W_emb = (const float*)d_in[6];
    const float* g_emb = (const float*)d_in[7];
    const float* beta_emb = (const float*)d_in[8];
    const float* anchors = (const float*)d_in[9];
    const float* Wc1 = (const float*)d_in[10];
    const float* bc1 = (const float*)d_in[11];
    const float* Wc2 = (const float*)d_in[12];
    const float* bc2 = (const float*)d_in[13];
    const float* g_c = (const float*)d_in[14];
    const float* beta_c = (const float*)d_in[15];
    const float* W_mod = (const float*)d_in[16];
    const float* b_mod = (const float*)d_in[17];
    const float* geo_gate = (const float*)d_in[18];
    const float* W_geo = (const float*)d_in[19];
    const float* b_geo = (const float*)d_in[20];
    const float* g_geo = (const float*)d_in[21];
    const float* beta_geo = (const float*)d_in[22];

    // d_out is FLOAT32: x_out = 16,777,216 f32 (67,108,864 B) + geo_out 8192 f32.
    // Scratch staged in d_out's first 28 MB; fully consumed before modulate
    // overwrites [0, 67,108,864) (stream-ordered). cw lives in d_ws.
    char* ob = (char*)d_out;
    u16* G = (u16*)(ob);                      // 16,777,216 B
    float* V = (float*)(ob + 16777216);       //  8,388,608 B -> 25,165,824
    float* cs = (float*)(ob + 25165824);      //     65,536 B -> 25,231,360
    float* svdraw = (float*)(ob + 25231360);  //      3,072 B -> 25,234,432
    float* tg = (float*)(ob + 25234432);      //      4,096 B -> 25,238,528
    float* pw = (float*)(ob + 25238528);      //     32,768 B -> 25,271,296
    float* ctxb = (float*)(ob + 25271296);    //     32,768 B -> 25,304,064
    float* cw = (float*)d_ws;                 //     65,536 B

    float* outx = (float*)d_out;
    float* outg = outx + 16777216;

    gram_kernel<<<dim3(16, 32), dim3(256), 0, stream>>>(x, G);
    colsum_kernel<<<dim3(4096), dim3(256), 0, stream>>>(x, cs);
    lanczos_kernel<<<dim3(32), dim3(1024), 0, stream>>>(G, V, svdraw);
    embgate_kernel<<<dim3(32), dim3(256), 0, stream>>>(cs, W_emb, g_emb, beta_emb, anchors, tg);
    mlp_kernel<<<dim3(32), dim3(256), 0, stream>>>(tg, Wc1, bc1, Wc2, bc2, g_c, beta_c, pw);
    ctx_kernel<<<dim3(32), dim3(256), 0, stream>>>(svdraw, W_svd, b_svd, g_svd, beta_svd, ctxb);
    cwgeo_kernel<<<dim3(32), dim3(256), 0, stream>>>(pw, ctxb, geo_state, W_mod, b_mod,
                                                     geo_gate, W_geo, b_geo, g_geo, beta_geo,
                                                     cw, outg);
    modulate_kernel<<<dim3(16384), dim3(256), 0, stream>>>(x, cw, outx);
}

// Round 9
// 1691.949 us; speedup vs baseline: 1.1883x; 1.1883x over previous
//
#include <hip/hip_runtime.h>
#include <hip/hip_bf16.h>

typedef unsigned short u16;
typedef unsigned int u32;
typedef __attribute__((ext_vector_type(8))) short short8;
typedef __attribute__((ext_vector_type(4))) float f32x4;

#define NB 32
#define NC_ 512
#define HW 1024
#define NE 256
#define NA 32
#define NR 24
#define PW_ 256
#define MLAN 128
#define NV 56  // Lanczos vectors cached in LDS (f32)

__device__ inline float b2f(u16 u) { return __uint_as_float(((u32)u) << 16); }
__device__ inline u16 f2b(float f) {
    u32 x = __float_as_uint(f);
    u32 r = x + 0x7FFFu + ((x >> 16) & 1u);
    return (u16)(r >> 16);
}
__device__ inline float gelu_exact(float x) {
    return 0.5f * x * (1.0f + erff(x * 0.70710678118654752f));
}
__device__ inline float sigmoidf_(float x) { return 1.0f / (1.0f + expf(-x)); }

template <int NW>
__device__ inline float block_reduce_sum(float x, volatile float* red) {
#pragma unroll
    for (int m = 32; m >= 1; m >>= 1) x += __shfl_xor(x, m);
    const int lane = threadIdx.x & 63, wid = threadIdx.x >> 6;
    __syncthreads();
    if (lane == 0) red[wid] = x;
    __syncthreads();
    float s = 0.f;
#pragma unroll
    for (int i = 0; i < NW; i++) s += red[i];
    return s;
}

// ---------------- Gram: G[b] = X_b X_b^T / 1024, row-major bf16 ----------------
__global__ __launch_bounds__(256) void gram_kernel(const float* __restrict__ x,
                                                   u16* __restrict__ Gp) {
    __shared__ __align__(16) u16 Ai[128][72];
    __shared__ __align__(16) u16 Bj[128][72];
    const int b = blockIdx.y;
    const int i0 = (blockIdx.x >> 2) * 128;
    const int j0 = (blockIdx.x & 3) * 128;
    const int t = threadIdx.x;
    const int lane = t & 63, wid = t >> 6;
    const int wm = (wid >> 1) * 64, wn = (wid & 1) * 64;
    f32x4 acc[4][4] = {};
    const float* xb = x + (size_t)b * NC_ * HW;

    for (int kc = 0; kc < HW; kc += 64) {
#pragma unroll
        for (int i = 0; i < 8; i++) {
            int idx = t + 256 * i;  // 128 rows x 16 float4
            int r = idx >> 4, c4 = (idx & 15) * 4;
            float4 qa = *(const float4*)(xb + (size_t)(i0 + r) * HW + kc + c4);
            float4 qb = *(const float4*)(xb + (size_t)(j0 + r) * HW + kc + c4);
            Ai[r][c4 + 0] = f2b(qa.x); Ai[r][c4 + 1] = f2b(qa.y);
            Ai[r][c4 + 2] = f2b(qa.z); Ai[r][c4 + 3] = f2b(qa.w);
            Bj[r][c4 + 0] = f2b(qb.x); Bj[r][c4 + 1] = f2b(qb.y);
            Bj[r][c4 + 2] = f2b(qb.z); Bj[r][c4 + 3] = f2b(qb.w);
        }
        __syncthreads();
#pragma unroll
        for (int ks = 0; ks < 64; ks += 32) {
            const int kk = ks + (lane >> 4) * 8;
            short8 af[4], bf[4];
#pragma unroll
            for (int m = 0; m < 4; m++) af[m] = *(const short8*)&Ai[wm + m * 16 + (lane & 15)][kk];
#pragma unroll
            for (int n = 0; n < 4; n++) bf[n] = *(const short8*)&Bj[wn + n * 16 + (lane & 15)][kk];
#pragma unroll
            for (int m = 0; m < 4; m++)
#pragma unroll
                for (int n = 0; n < 4; n++)
                    acc[m][n] = __builtin_amdgcn_mfma_f32_16x16x32_bf16(af[m], bf[n], acc[m][n], 0, 0, 0);
        }
        __syncthreads();
    }
    const float scale = 1.0f / 1024.0f;
    u16* Gb = Gp + (size_t)b * NC_ * NC_;
#pragma unroll
    for (int m = 0; m < 4; m++) {
#pragma unroll
        for (int n = 0; n < 4; n++) {
            int row = i0 + wm + m * 16 + (lane >> 4) * 4;
            int col = j0 + wn + n * 16 + (lane & 15);
#pragma unroll
            for (int r = 0; r < 4; r++)
                Gb[(size_t)(row + r) * NC_ + col] = f2b(acc[m][n][r] * scale);
        }
    }
}

// ---------------- channel sums ----------------
__global__ __launch_bounds__(256) void colsum_kernel(const float* __restrict__ x,
                                                     float* __restrict__ cs) {
    const int row = blockIdx.x * 4 + (threadIdx.x >> 6);
    const int lane = threadIdx.x & 63;
    const float* p = x + (size_t)row * HW;
    float s = 0.f;
    for (int i = lane; i < HW; i += 64) s += p[i];
#pragma unroll
    for (int m = 32; m >= 1; m >>= 1) s += __shfl_xor(s, m);
    if (lane == 0) cs[row] = s;
}

// ---------------- Lanczos (m=128) + Sturm bisection ----------------
// R9 = R6's proven streamed matvec (all 32 rows, no reg cache -- R7's VGPR
// cache was compiler-spilled to scratch: VGPR=64, WRITE_SIZE +5MB) combined
// with R7's reorth restructure, now cleanly isolated:
//  * Fused dot+scatter reorth: each wave dots AND subtracts its i-subset,
//    per-wave partial correction vectors in scr[16][544]; V read ONCE.
//  * Unnormalized basis + sc2[i]=1/beta^2 scale tracking; v normalized on
//    the fly from registers -> no v-publish barrier.
//  Skip path = 4 barriers/iter (S1 wpart+alpha, S2 w+nb0, SA partials,
//  SB norm+w'). Separate red/red2/red3 rails; all write/read pairs
//  barrier-separated.
__global__ __launch_bounds__(1024, 4) void lanczos_kernel(const u16* __restrict__ Gp,
                                                          float* __restrict__ V,
                                                          float* __restrict__ svd_raw) {
    __shared__ __align__(16) float Vl[NV][512];   // 114688 B (unnormalized r's)
    __shared__ __align__(16) float w[512];        // 2048 B (current r)
    __shared__ float v2[528];                     // 2112 B (r transposed, stride 66)
    __shared__ __align__(16) float scr[16][544];  // 34816 B (wpart / reorth partials)
    __shared__ float red[16], red2[8], red3[8];
    __shared__ float al[MLAN], be[MLAN + 1], sc2_[MLAN + 1];
    const int b = blockIdx.x;
    const int t = threadIdx.x;
    const int lane = t & 63, wid = t >> 6;
    const int el = t & 511, half = t >> 9;
    const int e8 = el & 7, l8 = el >> 3;
    const u16* Gb = Gp + (size_t)b * NC_ * NC_;
    const u16* gp = Gb + (size_t)(wid * 32) * NC_ + lane * 8;  // this thread's slab
    float* Vb = V + (size_t)b * MLAN * 512;

    u32 h = (u32)el * 2654435761u ^ ((u32)b * 0x9E3779B9u);
    h ^= h >> 16; h *= 0x85EBCA6Bu; h ^= h >> 13; h *= 0xC2B2AE35u; h ^= h >> 16;
    float vt0 = (float)(h & 0xFFFFFFu) * (1.0f / 16777216.0f) - 0.5f;
    float nrm = block_reduce_sum<16>(half == 0 ? vt0 * vt0 : 0.f, red);
    vt0 *= rsqrtf(nrm);
    if (half == 0) {
        w[el] = vt0;
        v2[e8 * 66 + l8] = vt0;
        Vl[0][el] = vt0;
    }
    if (t == 0) sc2_[0] = 1.0f;
    // per-thread scaled-basis state: rw/invc = current r element & 1/beta;
    // rwp/invp = previous. v_j[el] = rw*invc, v_{j-1}[el] = rwp*invp.
    float rw = vt0, invc = 1.0f, rwp = 0.f, invp = 0.f, beta = 0.f;
    __syncthreads();

    for (int j = 0; j < MLAN; j++) {
        // ---- matvec u' = G * r_{j-1}: coalesced 16B loads, 32-row slab ----
        float a0 = 0.f, a1 = 0.f, a2 = 0.f, a3 = 0.f;
        float a4 = 0.f, a5 = 0.f, a6 = 0.f, a7 = 0.f;
        const float* vk = w + wid * 32;
#pragma unroll 16
        for (int kk = 0; kk < 32; kk++) {
            short8 g = *(const short8*)(gp + (size_t)kk * NC_);
            float vv = vk[kk];
            a0 += b2f((u16)g[0]) * vv;
            a1 += b2f((u16)g[1]) * vv;
            a2 += b2f((u16)g[2]) * vv;
            a3 += b2f((u16)g[3]) * vv;
            a4 += b2f((u16)g[4]) * vv;
            a5 += b2f((u16)g[5]) * vv;
            a6 += b2f((u16)g[6]) * vv;
            a7 += b2f((u16)g[7]) * vv;
        }
        // wpart: column c = lane*8+e -> scr[wid][e*68+lane]
        scr[wid][0 * 68 + lane] = a0; scr[wid][1 * 68 + lane] = a1;
        scr[wid][2 * 68 + lane] = a2; scr[wid][3 * 68 + lane] = a3;
        scr[wid][4 * 68 + lane] = a4; scr[wid][5 * 68 + lane] = a5;
        scr[wid][6 * 68 + lane] = a6; scr[wid][7 * 68 + lane] = a7;
        // alpha partial: u' . r  via transposed copy v2 (conflict-free b32)
        float ap = a0 * v2[lane] + a1 * v2[66 + lane]
                 + a2 * v2[132 + lane] + a3 * v2[198 + lane]
                 + a4 * v2[264 + lane] + a5 * v2[330 + lane]
                 + a6 * v2[396 + lane] + a7 * v2[462 + lane];
#pragma unroll
        for (int m = 32; m >= 1; m >>= 1) ap += __shfl_xor(ap, m);
        if (lane == 0) red[wid] = ap;
        __syncthreads();  // S1: wpart + alpha partials

        float accp = 0.f;
#pragma unroll
        for (int p = 0; p < 16; p++) accp += scr[p][e8 * 68 + l8];  // u'_el
        float rawa = 0.f;
#pragma unroll
        for (int i = 0; i < 16; i++) rawa += red[i];  // u' . r
        const float alpha = rawa * invc * invc;
        float wt = accp * invc - alpha * (rw * invc) - beta * (rwp * invp);
        if (half == 0) w[el] = wt;
        float pz = wt * wt;
#pragma unroll
        for (int m = 32; m >= 1; m >>= 1) pz += __shfl_xor(pz, m);
        if (lane == 0 && wid < 8) red2[wid] = pz;
        __syncthreads();  // S2: w + nb0 partials
        float nb0 = 0.f;
#pragma unroll
        for (int i = 0; i < 8; i++) nb0 += red2[i];
        const float gscale = nb0 + alpha * alpha + beta * beta;

        float nb = 0.f;
        for (int pass = 0;; pass++) {
            // ---- fused dots + scatter: wave handles i in {wid, wid+16, ...} ----
            const float4 wv0 = *(const float4*)&w[lane * 4];
            const float4 wv1 = *(const float4*)&w[256 + lane * 4];
            float s0 = 0.f, s1 = 0.f, s2 = 0.f, s3 = 0.f;
            float s4 = 0.f, s5 = 0.f, s6 = 0.f, s7 = 0.f;
            for (int i = wid; i <= j; i += 16) {
                float4 x0, x1;
                if (i < NV) {
                    x0 = *(const float4*)&Vl[i][lane * 4];
                    x1 = *(const float4*)&Vl[i][256 + lane * 4];
                } else {
                    const float* Vi = Vb + (size_t)i * 512;
                    x0 = *(const float4*)(Vi + lane * 4);
                    x1 = *(const float4*)(Vi + 256 + lane * 4);
                }
                float p = x0.x * wv0.x + x0.y * wv0.y + x0.z * wv0.z + x0.w * wv0.w
                        + x1.x * wv1.x + x1.y * wv1.y + x1.z * wv1.z + x1.w * wv1.w;
#pragma unroll
                for (int m = 32; m >= 1; m >>= 1) p += __shfl_xor(p, m);
                const float ps = p * sc2_[i];  // <v_i,w> scale (unnormalized basis)
                s0 += ps * x0.x; s1 += ps * x0.y; s2 += ps * x0.z; s3 += ps * x0.w;
                s4 += ps * x1.x; s5 += ps * x1.y; s6 += ps * x1.z; s7 += ps * x1.w;
            }
            *(f32x4*)&scr[wid][lane * 4] = (f32x4){s0, s1, s2, s3};
            *(f32x4*)&scr[wid][256 + lane * 4] = (f32x4){s4, s5, s6, s7};
            __syncthreads();  // SA: partial corrections
            float sub = 0.f;
#pragma unroll
            for (int p16 = 0; p16 < 16; p16++) sub += scr[p16][el];
            wt = wt - sub;
            if (half == 0) {
                w[el] = wt;  // for (rare) pass 2 / next matvec
                v2[e8 * 66 + l8] = wt;
                if (j + 1 < NV) Vl[j + 1][el] = wt;
                else if (j + 1 < MLAN) Vb[(size_t)(j + 1) * 512 + el] = wt;
            }
            float pn = wt * wt;
#pragma unroll
            for (int m = 32; m >= 1; m >>= 1) pn += __shfl_xor(pn, m);
            if (lane == 0 && wid < 8) red3[wid] = pn;
            __syncthreads();  // SB: norm partials + w/v2/Vl
            nb = 0.f;
#pragma unroll
            for (int q = 0; q < 8; q++) nb += red3[q];
            // DGKS "twice is enough" with absolute cancellation guard
            if (pass == 1 || (nb > 0.5f * nb0 && nb0 > 1e-8f * gscale)) break;
            nb0 = nb;
        }
        float betn = sqrtf(nb);
        bool ok = (betn > 1e-20f) && (betn == betn) && !isinf(betn);
        if (t == 0) {
            al[j] = alpha;
            be[j + 1] = ok ? betn : 0.f;
            sc2_[j + 1] = ok ? 1.0f / nb : 0.f;
        }
        beta = ok ? betn : 0.f;
        rwp = rw; invp = invc;
        rw = wt;
        invc = ok ? 1.0f / betn : 0.f;
        // no barrier: next matvec reads w/v2 published before SB; sc2_[j+1]
        // and red rails are separated from their readers by >=1 barrier.
    }

    if (t < NR) {
        float lo = 1e30f, hi = -1e30f;
        for (int i = 0; i < MLAN; i++) {
            float bl = (i > 0) ? fabsf(be[i]) : 0.f;
            float br = (i + 1 < MLAN) ? fabsf(be[i + 1]) : 0.f;
            lo = fminf(lo, al[i] - bl - br);
            hi = fmaxf(hi, al[i] + bl + br);
        }
        const int i0 = MLAN - 1 - t;
        for (int it = 0; it < 30; it++) {
            float mid = 0.5f * (lo + hi);
            int cnt = 0;
            float d = 1.0f;
            for (int i = 0; i < MLAN; i++) {
                float bb2 = (i > 0) ? be[i] * be[i] : 0.f;
                float dp = d;
                if (fabsf(dp) < 1e-30f) dp = (dp < 0.f) ? -1e-30f : 1e-30f;
                d = (al[i] - mid) - bb2 / dp;
                cnt += (d < 0.f);
            }
            if (cnt > i0) hi = mid; else lo = mid;
        }
        float ev = fmaxf(0.5f * (lo + hi), 0.f);
        float val = log1pf(sqrtf(ev));
        if (!(val == val) || isinf(val)) val = 1.0f;
        svd_raw[b * NR + t] = val;
    }
}

// ---------------- emb -> cos -> top3 -> gate ----------------
__global__ __launch_bounds__(256) void embgate_kernel(
    const float* __restrict__ cs, const float* __restrict__ W_emb,
    const float* __restrict__ g_emb, const float* __restrict__ beta_emb,
    const float* __restrict__ anchors, float* __restrict__ tg_out) {
    const int b = blockIdx.x, t = threadIdx.x;
    __shared__ float csl[512], embv[256], cosv[32], tgs[32];
    __shared__ float red[4];

    for (int i = t; i < 512; i += 256) csl[i] = cs[b * 512 + i];
    __syncthreads();

    float e = 0.f;
    for (int c = 0; c < 512; c++) e += csl[c] * W_emb[c * NE + t];
    e *= (1.0f / 1024.0f);
    float mean = block_reduce_sum<4>(e, red) * (1.0f / 256.0f);
    float dv = e - mean;
    float var = block_reduce_sum<4>(dv * dv, red) * (1.0f / 256.0f);
    e = dv * rsqrtf(var + 1e-5f) * g_emb[t] + beta_emb[t];
    float nn = block_reduce_sum<4>(e * e, red);
    e = e / fmaxf(sqrtf(nn), 1e-12f);
    embv[t] = e;
    __syncthreads();

    if (t < 32) {
        float p = 0.f, na = 0.f;
        for (int q = 0; q < 256; q++) {
            float av = anchors[t * NE + q];
            p += embv[q] * av;
            na += av * av;
        }
        cosv[t] = p / fmaxf(sqrtf(na), 1e-12f);
    }
    __syncthreads();

    if (t == 0) {
        int i1 = 0, i2 = 0, i3 = 0;
        float v1 = -1e30f, v2 = -1e30f, v3 = -1e30f;
        for (int a = 0; a < 32; a++) {
            float cv = cosv[a];
            if (cv > v1) { v3 = v2; i3 = i2; v2 = v1; i2 = i1; v1 = cv; i1 = a; }
            else if (cv > v2) { v3 = v2; i3 = i2; v2 = cv; i2 = a; }
            else if (cv > v3) { v3 = cv; i3 = a; }
        }
        float e2 = expf(v2 - v1), e3 = expf(v3 - v1);
        float ss = 1.0f + e2 + e3;
        for (int a = 0; a < 32; a++) tgs[a] = 0.f;
        tgs[i1] = (1.0f - v1) * 1.0f / ss;
        tgs[i2] = (1.0f - v2) * e2 / ss;
        tgs[i3] = (1.0f - v3) * e3 / ss;
    }
    __syncthreads();
    if (t < 32) tg_out[b * 32 + t] = tgs[t];
}

// ---------------- compartment MLPs -> pw ----------------
__global__ __launch_bounds__(256) void mlp_kernel(
    const float* __restrict__ tg, const float* __restrict__ Wc1,
    const float* __restrict__ bc1, const float* __restrict__ Wc2,
    const float* __restrict__ bc2, const float* __restrict__ g_c,
    const float* __restrict__ beta_c, float* __restrict__ pw_out) {
    const int b = blockIdx.x, t = threadIdx.x;
    __shared__ float tgl[32], hbuf[512], pcb[256];

    if (t < 32) tgl[t] = tg[b * 32 + t];
    __syncthreads();

    for (int o = t; o < 512; o += 256) {
        int c = o >> 6, d = o & 63;
        float s = bc1[c * 64 + d];
        for (int a = 0; a < 32; a++) s += tgl[a] * Wc1[(c * 32 + a) * 64 + d];
        hbuf[o] = gelu_exact(s);
    }
    __syncthreads();

    const int c = t >> 5, e = t & 31;
    float s = bc2[c * 32 + e];
    for (int d = 0; d < 64; d++) s += hbuf[c * 64 + d] * Wc2[(c * 64 + d) * 32 + e];
    pcb[t] = s;
    __syncthreads();

    float mean = 0.f;
    for (int k = 0; k < 32; k++) mean += pcb[c * 32 + k];
    mean *= (1.0f / 32.0f);
    float var = 0.f;
    for (int k = 0; k < 32; k++) { float dd = pcb[c * 32 + k] - mean; var += dd * dd; }
    var *= (1.0f / 32.0f);
    pw_out[b * PW_ + t] = (s - mean) * rsqrtf(var + 1e-5f) * g_c[c * 32 + e] + beta_c[c * 32 + e];
}

// ---------------- svd_ctx ----------------
__global__ __launch_bounds__(256) void ctx_kernel(
    const float* __restrict__ svd_raw, const float* __restrict__ W_svd,
    const float* __restrict__ b_svd, const float* __restrict__ g_svd,
    const float* __restrict__ beta_svd, float* __restrict__ ctx_out) {
    const int b = blockIdx.x, t = threadIdx.x;
    __shared__ float rawv[NR];
    __shared__ float red[4];
    if (t < NR) rawv[t] = svd_raw[b * NR + t];
    __syncthreads();
    float sv = b_svd[t];
    for (int r = 0; r < NR; r++) sv += rawv[r] * W_svd[r * PW_ + t];
    float mean = block_reduce_sum<4>(sv, red) * (1.0f / 256.0f);
    float dv = sv - mean;
    float var = block_reduce_sum<4>(dv * dv, red) * (1.0f / 256.0f);
    ctx_out[b * PW_ + t] = gelu_exact(dv * rsqrtf(var + 1e-5f) * g_svd[t] + beta_svd[t]);
}

// ---------------- cw + geo_out (f32) ----------------
__global__ __launch_bounds__(256) void cwgeo_kernel(
    const float* __restrict__ pw, const float* __restrict__ ctx,
    const float* __restrict__ geo_state, const float* __restrict__ W_mod,
    const float* __restrict__ b_mod, const float* __restrict__ geo_gate,
    const float* __restrict__ W_geo, const float* __restrict__ b_geo,
    const float* __restrict__ g_geo, const float* __restrict__ beta_geo,
    float* __restrict__ cw, float* __restrict__ out_geo) {
    const int b = blockIdx.x, t = threadIdx.x;
    __shared__ float mi[768];
    __shared__ float red[4];
    mi[t] = pw[b * PW_ + t];
    mi[256 + t] = ctx[b * PW_ + t];
    float geo = geo_state[b * PW_ + t];
    mi[512 + t] = geo;
    __syncthreads();

    float gg = b_geo[t];
    for (int q = 0; q < PW_; q++) gg += mi[q] * W_geo[q * PW_ + t];
    float gmean = block_reduce_sum<4>(gg, red) * (1.0f / 256.0f);
    float gdv = gg - gmean;
    float gvar = block_reduce_sum<4>(gdv * gdv, red) * (1.0f / 256.0f);
    float lnv = gdv * rsqrtf(gvar + 1e-5f) * g_geo[t] + beta_geo[t];
    out_geo[b * PW_ + t] = geo + sigmoidf_(geo_gate[t]) * lnv;

    for (int c = t; c < 512; c += 256) {
        float s = b_mod[c];
        for (int k = 0; k < 768; k++) s += mi[k] * W_mod[k * NC_ + c];
        cw[b * NC_ + c] = sigmoidf_(s);
    }
}

// ---------------- x_out(f32) = x(f32) * cw[b,c] ----------------
__global__ __launch_bounds__(256) void modulate_kernel(const float* __restrict__ x,
                                                       const float* __restrict__ cw,
                                                       float* __restrict__ out) {
    const int i4 = blockIdx.x * 256 + threadIdx.x;  // float4 index
    const float4* xp = (const float4*)x;
    float4 q = xp[i4];
    const float wv = cw[i4 >> 8];  // (i4*4)>>10 = b*512+c
    float4 o;
    o.x = q.x * wv; o.y = q.y * wv; o.z = q.z * wv; o.w = q.w * wv;
    ((float4*)out)[i4] = o;
}

extern "C" void kernel_launch(void* const* d_in, const int* in_sizes, int n_in,
                              void* d_out, int out_size, void* d_ws, size_t ws_size,
                              hipStream_t stream) {
    const float* x = (const float*)d_in[0];
    const float* geo_state = (const float*)d_in[1];
    const float* W_svd = (const float*)d_in[2];
    const float* b_svd = (const float*)d_in[3];
    const float* g_svd = (const float*)d_in[4];
    const float* beta_svd = (const float*)d_in[5];
    const float* W_emb = (const float*)d_in[6];
    const float* g_emb = (const float*)d_in[7];
    const float* beta_emb = (const float*)d_in[8];
    const float* anchors = (const float*)d_in[9];
    const float* Wc1 = (const float*)d_in[10];
    const float* bc1 = (const float*)d_in[11];
    const float* Wc2 = (const float*)d_in[12];
    const float* bc2 = (const float*)d_in[13];
    const float* g_c = (const float*)d_in[14];
    const float* beta_c = (const float*)d_in[15];
    const float* W_mod = (const float*)d_in[16];
    const float* b_mod = (const float*)d_in[17];
    const float* geo_gate = (const float*)d_in[18];
    const float* W_geo = (const float*)d_in[19];
    const float* b_geo = (const float*)d_in[20];
    const float* g_geo = (const float*)d_in[21];
    const float* beta_geo = (const float*)d_in[22];

    // d_out is FLOAT32: x_out = 16,777,216 f32 (67,108,864 B) + geo_out 8192 f32.
    // Scratch staged in d_out's first 28 MB; fully consumed before modulate
    // overwrites [0, 67,108,864) (stream-ordered). cw lives in d_ws.
    char* ob = (char*)d_out;
    u16* G = (u16*)(ob);                      // 16,777,216 B
    float* V = (float*)(ob + 16777216);       //  8,388,608 B -> 25,165,824
    float* cs = (float*)(ob + 25165824);      //     65,536 B -> 25,231,360
    float* svdraw = (float*)(ob + 25231360);  //      3,072 B -> 25,234,432
    float* tg = (float*)(ob + 25234432);      //      4,096 B -> 25,238,528
    float* pw = (float*)(ob + 25238528);      //     32,768 B -> 25,271,296
    float* ctxb = (float*)(ob + 25271296);    //     32,768 B -> 25,304,064
    float* cw = (float*)d_ws;                 //     65,536 B

    float* outx = (float*)d_out;
    float* outg = outx + 16777216;

    gram_kernel<<<dim3(16, 32), dim3(256), 0, stream>>>(x, G);
    colsum_kernel<<<dim3(4096), dim3(256), 0, stream>>>(x, cs);
    lanczos_kernel<<<dim3(32), dim3(1024), 0, stream>>>(G, V, svdraw);
    embgate_kernel<<<dim3(32), dim3(256), 0, stream>>>(cs, W_emb, g_emb, beta_emb, anchors, tg);
    mlp_kernel<<<dim3(32), dim3(256), 0, stream>>>(tg, Wc1, bc1, Wc2, bc2, g_c, beta_c, pw);
    ctx_kernel<<<dim3(32), dim3(256), 0, stream>>>(svdraw, W_svd, b_svd, g_svd, beta_svd, ctxb);
    cwgeo_kernel<<<dim3(32), dim3(256), 0, stream>>>(pw, ctxb, geo_state, W_mod, b_mod,
                                                     geo_gate, W_geo, b_geo, g_geo, beta_geo,
                                                     cw, outg);
    modulate_kernel<<<dim3(16384), dim3(256), 0, stream>>>(x, cw, outx);
}